// Round 1
// baseline (3360.905 us; speedup 1.0000x reference)
//
#include <hip/hip_runtime.h>
#include <hip/hip_bf16.h>
#include <cmath>

typedef unsigned int u32;
typedef unsigned short u16;
typedef _Float16 f16;
typedef f16 h2 __attribute__((ext_vector_type(2)));
typedef short bf16x8 __attribute__((ext_vector_type(8)));
typedef float f32x4 __attribute__((ext_vector_type(4)));

// ---------- sizes ----------
#define Bn 64
#define Tn 1024
#define IDIM 80
#define Hn 256
#define G3 768           // 3*H
#define STOK 5
#define SDIM 128
#define MROWS (Bn*Tn)    // 65536

// ---------- helpers ----------
__device__ __forceinline__ float bf2f(u16 v) { return __uint_as_float(((u32)v) << 16); }
__device__ __forceinline__ u16 f2bf(float f) {
  u32 x = __float_as_uint(f);
  return (u16)((x + 0x7FFFu + ((x >> 16) & 1u)) >> 16);   // RNE
}
__device__ __forceinline__ float fdot2f(h2 a, h2 b, float c) {
#if __has_builtin(__builtin_amdgcn_fdot2)
  return __builtin_amdgcn_fdot2(a, b, c, false);
#else
  return c + (float)a[0] * (float)b[0] + (float)a[1] * (float)b[1];
#endif
}

// ---------- conversion kernels ----------
__global__ void k_cvt_bf16(const float* __restrict__ in, u16* __restrict__ out, int n) {
  int i = blockIdx.x * blockDim.x + threadIdx.x;
  int st = gridDim.x * blockDim.x;
  for (; i < n; i += st) out[i] = f2bf(in[i]);
}
__global__ void k_cvt_f16(const float* __restrict__ in, u16* __restrict__ out, int n) {
  int i = blockIdx.x * blockDim.x + threadIdx.x;
  int st = gridDim.x * blockDim.x;
  for (; i < n; i += st) {
    union { f16 h; u16 u; } cv;
    cv.h = (f16)in[i];
    out[i] = cv.u;
  }
}

// ---------- k/v projection (tiny: 5x256 each) ----------
__global__ __launch_bounds__(256) void k_kv(const float* __restrict__ st,
                                            const float* __restrict__ kw,
                                            const float* __restrict__ vw,
                                            const float* __restrict__ inb,
                                            float* __restrict__ kv) {
  int e = threadIdx.x;   // 0..255
  for (int s = 0; s < STOK; ++s) {
    float ak = inb[Hn + e], av = inb[2 * Hn + e];
    for (int d = 0; d < SDIM; ++d) {
      float x = st[s * SDIM + d];
      ak += x * kw[e * SDIM + d];
      av += x * vw[e * SDIM + d];
    }
    kv[s * Hn + e] = ak;
    kv[STOK * Hn + s * Hn + e] = av;
  }
}

// ---------- MFMA GEMM: C[m][n] = scale*(sum_k A[m][k]*B[n][k] + bias[n]) ----------
// A: [M][K] bf16, B: [N][K] bf16 (i.e. X @ W^T). M,N multiples of 128, K arbitrary.
template <bool OUT_BF16>
__global__ __launch_bounds__(256) void k_gemm_bt(const u16* __restrict__ A,
                                                 const u16* __restrict__ B,
                                                 const float* __restrict__ bias,
                                                 float scale, void* __restrict__ Cout,
                                                 int M, int N, int K) {
  constexpr int BM = 128, BN = 128, BK = 32, LDT = 40;  // pad 32->40 elems (80B rows, 16B aligned)
  __shared__ __align__(16) u16 As[BM * LDT];
  __shared__ __align__(16) u16 Bs[BN * LDT];
  const int tid = threadIdx.x;
  const int bm0 = blockIdx.x * BM;
  const int bn0 = blockIdx.y * BN;
  const int lane = tid & 63;
  const int wave = tid >> 6;
  const int wm = (wave & 1) * 64;
  const int wn = (wave >> 1) * 64;
  const int lr = lane & 15;
  const int kg = lane >> 4;
  const int srow = tid >> 1, sch = tid & 1;

  f32x4 acc[4][4] = {};

  for (int k0 = 0; k0 < K; k0 += BK) {
    // stage A tile
    {
      const u16* gp = A + (size_t)(bm0 + srow) * K + k0 + sch * 16;
      u16* lp = &As[srow * LDT + sch * 16];
      if (k0 + BK <= K) {
        *(uint4*)lp = *(const uint4*)gp;
        *(uint4*)(lp + 8) = *(const uint4*)(gp + 8);
      } else {
        for (int i = 0; i < 16; ++i) {
          int k = k0 + sch * 16 + i;
          lp[i] = (k < K) ? gp[i] : (u16)0;
        }
      }
    }
    // stage B tile
    {
      const u16* gp = B + (size_t)(bn0 + srow) * K + k0 + sch * 16;
      u16* lp = &Bs[srow * LDT + sch * 16];
      if (k0 + BK <= K) {
        *(uint4*)lp = *(const uint4*)gp;
        *(uint4*)(lp + 8) = *(const uint4*)(gp + 8);
      } else {
        for (int i = 0; i < 16; ++i) {
          int k = k0 + sch * 16 + i;
          lp[i] = (k < K) ? gp[i] : (u16)0;
        }
      }
    }
    __syncthreads();

    bf16x8 af[4], bfr[4];
#pragma unroll
    for (int mi = 0; mi < 4; ++mi)
      af[mi] = *(const bf16x8*)&As[(wm + mi * 16 + lr) * LDT + kg * 8];
#pragma unroll
    for (int ni = 0; ni < 4; ++ni)
      bfr[ni] = *(const bf16x8*)&Bs[(wn + ni * 16 + lr) * LDT + kg * 8];
#pragma unroll
    for (int mi = 0; mi < 4; ++mi)
#pragma unroll
      for (int ni = 0; ni < 4; ++ni)
        acc[mi][ni] = __builtin_amdgcn_mfma_f32_16x16x32_bf16(af[mi], bfr[ni], acc[mi][ni], 0, 0, 0);
    __syncthreads();
  }

  // epilogue: D mapping col=lane&15, row=(lane>>4)*4+reg  [m89/m91 verified]
#pragma unroll
  for (int mi = 0; mi < 4; ++mi)
#pragma unroll
    for (int ni = 0; ni < 4; ++ni)
#pragma unroll
      for (int r = 0; r < 4; ++r) {
        int row = bm0 + wm + mi * 16 + kg * 4 + r;
        int col = bn0 + wn + ni * 16 + lr;
        float v = acc[mi][ni][r];
        if (bias) v += bias[col];
        v *= scale;
        if (OUT_BF16)
          ((u16*)Cout)[(size_t)row * N + col] = f2bf(v);
        else
          ((float*)Cout)[(size_t)row * N + col] = v;
      }
}

// ---------- GRU scan: one workgroup per batch element, weights register-resident ----------
// Whh2: [768][128] f16-pairs (row j = Whh[j][0..256) as 128 packed half2)
// xg:   [B][T][768] bf16 (x @ Wih^T + bih, precomputed)
// outs: [B][T][256] bf16
__global__ __launch_bounds__(768, 3) void k_gru(const u32* __restrict__ Whh2,
                                                const float* __restrict__ bhh,
                                                const u16* __restrict__ xg,
                                                u16* __restrict__ outs) {
  const int tid = threadIdx.x;   // 0..767 : gate index j
  const int b = blockIdx.x;      // batch element
  __shared__ __align__(16) f16 hsh[Hn];     // h in f16 for dot2
  __shared__ float ght[G3];
  __shared__ float xgl[G3];

  // load this gate's 256 weights into registers (128 half2 = 128 VGPRs)
  h2 hw[128];
  const h2* wrow = (const h2*)(Whh2 + (size_t)tid * 128);
#pragma unroll
  for (int i = 0; i < 128; ++i) hw[i] = wrow[i];
  const float bh = bhh[tid];

  float hreg = 0.f;
  if (tid < Hn) hsh[tid] = (f16)0.f;

  const u16* xgb = xg + (size_t)b * Tn * G3;
  u16* ob = outs + (size_t)b * Tn * Hn;
  float xcur = bf2f(xgb[tid]);   // t = 0
  __syncthreads();

  for (int t = 0; t < Tn; ++t) {
    // prefetch next step's xg (independent of h -> latency hidden under dot chain)
    float xnext = (t < Tn - 1) ? bf2f(xgb[(size_t)(t + 1) * G3 + tid]) : 0.f;

    // gh[j] = Whh[j,:] . h + bhh[j]   (h broadcast from LDS)
    const h2* hp = (const h2*)hsh;
    float a0 = bh, a1 = 0.f, a2 = 0.f, a3 = 0.f;
#pragma unroll
    for (int i = 0; i < 32; ++i) {
      a0 = fdot2f(hw[4 * i + 0], hp[4 * i + 0], a0);
      a1 = fdot2f(hw[4 * i + 1], hp[4 * i + 1], a1);
      a2 = fdot2f(hw[4 * i + 2], hp[4 * i + 2], a2);
      a3 = fdot2f(hw[4 * i + 3], hp[4 * i + 3], a3);
    }
    ght[tid] = (a0 + a1) + (a2 + a3);
    xgl[tid] = xcur;
    __syncthreads();

    if (tid < Hn) {
      float xr = xgl[tid], xz = xgl[Hn + tid], xn = xgl[2 * Hn + tid];
      float gr = ght[tid], gz = ght[Hn + tid], gn = ght[2 * Hn + tid];
      float r = 1.f / (1.f + __expf(-(xr + gr)));
      float z = 1.f / (1.f + __expf(-(xz + gz)));
      float n = tanhf(xn + r * gn);
      hreg = (1.f - z) * n + z * hreg;
      ob[(size_t)t * Hn + tid] = f2bf(hreg);
      hsh[tid] = (f16)hreg;
    }
    __syncthreads();
    xcur = xnext;
  }
}

// ---------- attention over 5 style tokens (thread per (b,t) row) ----------
__global__ __launch_bounds__(256) void k_attn(const u16* __restrict__ q,
                                              const float* __restrict__ kv,
                                              u16* __restrict__ ctx) {
  __shared__ float ks[STOK * Hn], vs[STOK * Hn];
  int tid = threadIdx.x;
  for (int i = tid; i < STOK * Hn; i += 256) {
    ks[i] = kv[i];
    vs[i] = kv[STOK * Hn + i];
  }
  __syncthreads();
  size_t row = (size_t)blockIdx.x * 256 + tid;   // b*T + t
  const u16* qr = q + row * Hn;
  u16* cr = ctx + row * Hn;
#pragma unroll
  for (int h = 0; h < 4; ++h) {
    float sc[STOK] = {0.f, 0.f, 0.f, 0.f, 0.f};
    for (int d = 0; d < 64; ++d) {
      float qv = bf2f(qr[h * 64 + d]);
#pragma unroll
      for (int s = 0; s < STOK; ++s) sc[s] += qv * ks[s * Hn + h * 64 + d];
    }
    float m = sc[0];
#pragma unroll
    for (int s = 1; s < STOK; ++s) m = fmaxf(m, sc[s]);
    float p[STOK], sum = 0.f;
#pragma unroll
    for (int s = 0; s < STOK; ++s) { p[s] = __expf(sc[s] - m); sum += p[s]; }
    float inv = 1.f / sum;
    for (int e = 0; e < 64; ++e) {
      float c = 0.f;
#pragma unroll
      for (int s = 0; s < STOK; ++s) c += p[s] * vs[s * Hn + h * 64 + e];
      cr[h * 64 + e] = f2bf(c * inv);
    }
  }
}

// ---------- workspace layout (bytes) ----------
#define WS_XG   ((size_t)0)                         // [B][T][768] bf16 = 100,663,296
#define WS_O0   ((size_t)100663296)                 // [B][T][256] bf16 = 33,554,432
#define WS_O1   ((size_t)134217728)                 // 33,554,432
#define WS_FB   ((size_t)167772160)                 // feats bf16 = 10,485,760
#define WS_W0   ((size_t)178257920)                 // Wih0 bf16 = 122,880
#define WS_W1   ((size_t)178380800)                 // Wih1 bf16 = 393,216
#define WS_QW   ((size_t)178774016)                 // q_w bf16 = 131,072
#define WS_OW   ((size_t)178905088)                 // out_w bf16 = 131,072
#define WS_H0   ((size_t)179036160)                 // Whh0 f16 = 393,216
#define WS_H1   ((size_t)179429376)                 // Whh1 f16 = 393,216
#define WS_KV   ((size_t)179822592)                 // k,v f32 = 10,240
// q and ctx alias the (dead-by-then) xg region:
#define WS_QB   ((size_t)0)                         // [B*T][256] bf16
#define WS_CTX  ((size_t)33554432)                  // [B*T][256] bf16

extern "C" void kernel_launch(void* const* d_in, const int* in_sizes, int n_in,
                              void* d_out, int out_size, void* d_ws, size_t ws_size,
                              hipStream_t stream) {
  const float* feats = (const float*)d_in[0];
  const float* style = (const float*)d_in[1];
  const float* Wih0 = (const float*)d_in[2];
  const float* Whh0 = (const float*)d_in[3];
  const float* bih0 = (const float*)d_in[4];
  const float* bhh0 = (const float*)d_in[5];
  const float* Wih1 = (const float*)d_in[6];
  const float* Whh1 = (const float*)d_in[7];
  const float* bih1 = (const float*)d_in[8];
  const float* bhh1 = (const float*)d_in[9];
  const float* q_w = (const float*)d_in[10];
  const float* k_w = (const float*)d_in[11];
  const float* v_w = (const float*)d_in[12];
  const float* in_b = (const float*)d_in[13];
  const float* out_w = (const float*)d_in[14];
  const float* out_b = (const float*)d_in[15];

  char* ws = (char*)d_ws;
  u16* xg = (u16*)(ws + WS_XG);
  u16* o0 = (u16*)(ws + WS_O0);
  u16* o1 = (u16*)(ws + WS_O1);
  u16* fb = (u16*)(ws + WS_FB);
  u16* w0 = (u16*)(ws + WS_W0);
  u16* w1 = (u16*)(ws + WS_W1);
  u16* qw = (u16*)(ws + WS_QW);
  u16* ow = (u16*)(ws + WS_OW);
  u16* h0 = (u16*)(ws + WS_H0);
  u16* h1 = (u16*)(ws + WS_H1);
  float* kv = (float*)(ws + WS_KV);
  u16* qb = (u16*)(ws + WS_QB);
  u16* ctx = (u16*)(ws + WS_CTX);

  auto cvgrid = [](int n) { int g = (n + 255) / 256; return g > 2048 ? 2048 : g; };

  // conversions
  k_cvt_bf16<<<cvgrid(MROWS * IDIM), 256, 0, stream>>>(feats, fb, MROWS * IDIM);
  k_cvt_bf16<<<cvgrid(G3 * IDIM), 256, 0, stream>>>(Wih0, w0, G3 * IDIM);
  k_cvt_bf16<<<cvgrid(G3 * Hn), 256, 0, stream>>>(Wih1, w1, G3 * Hn);
  k_cvt_bf16<<<cvgrid(Hn * Hn), 256, 0, stream>>>(q_w, qw, Hn * Hn);
  k_cvt_bf16<<<cvgrid(Hn * Hn), 256, 0, stream>>>(out_w, ow, Hn * Hn);
  k_cvt_f16<<<cvgrid(G3 * Hn), 256, 0, stream>>>(Whh0, h0, G3 * Hn);
  k_cvt_f16<<<cvgrid(G3 * Hn), 256, 0, stream>>>(Whh1, h1, G3 * Hn);

  // k/v projections
  k_kv<<<1, 256, 0, stream>>>(style, k_w, v_w, in_b, kv);

  dim3 g768(MROWS / 128, G3 / 128);
  dim3 g256(MROWS / 128, Hn / 128);

  // layer 0
  k_gemm_bt<true><<<g768, 256, 0, stream>>>(fb, w0, bih0, 1.f, xg, MROWS, G3, IDIM);
  k_gru<<<Bn, G3, 0, stream>>>((const u32*)h0, bhh0, xg, o0);
  // layer 1
  k_gemm_bt<true><<<g768, 256, 0, stream>>>(o0, w1, bih1, 1.f, xg, MROWS, G3, Hn);
  k_gru<<<Bn, G3, 0, stream>>>((const u32*)h1, bhh1, xg, o1);
  // attention
  k_gemm_bt<true><<<g256, 256, 0, stream>>>(o1, qw, in_b, 0.125f, qb, MROWS, Hn, Hn);
  k_attn<<<MROWS / 256, 256, 0, stream>>>(qb, kv, ctx);
  // output projection
  k_gemm_bt<false><<<g256, 256, 0, stream>>>(ctx, ow, out_b, 1.f, d_out, MROWS, Hn, Hn);
}

// Round 2
// 3067.096 us; speedup vs baseline: 1.0958x; 1.0958x over previous
//
#include <hip/hip_runtime.h>
#include <hip/hip_bf16.h>
#include <cmath>

typedef unsigned int u32;
typedef unsigned short u16;
typedef _Float16 f16;
typedef f16 h2 __attribute__((ext_vector_type(2)));
typedef f16 h8 __attribute__((ext_vector_type(8)));
typedef short bf16x8 __attribute__((ext_vector_type(8)));
typedef float f32x4 __attribute__((ext_vector_type(4)));

// ---------- sizes ----------
#define Bn 64
#define Tn 1024
#define IDIM 80
#define Hn 256
#define G3 768           // 3*H
#define STOK 5
#define SDIM 128
#define MROWS (Bn*Tn)    // 65536

// ---------- helpers ----------
__device__ __forceinline__ float bf2f(u16 v) { return __uint_as_float(((u32)v) << 16); }
__device__ __forceinline__ u16 f2bf(float f) {
  u32 x = __float_as_uint(f);
  return (u16)((x + 0x7FFFu + ((x >> 16) & 1u)) >> 16);   // RNE
}
__device__ __forceinline__ float fdot2f(h2 a, h2 b, float c) {
#if __has_builtin(__builtin_amdgcn_fdot2)
  return __builtin_amdgcn_fdot2(a, b, c, false);
#else
  return c + (float)a[0] * (float)b[0] + (float)a[1] * (float)b[1];
#endif
}

// ---------- conversion kernels ----------
__global__ void k_cvt_bf16(const float* __restrict__ in, u16* __restrict__ out, int n) {
  int i = blockIdx.x * blockDim.x + threadIdx.x;
  int st = gridDim.x * blockDim.x;
  for (; i < n; i += st) out[i] = f2bf(in[i]);
}
__global__ void k_cvt_f16(const float* __restrict__ in, u16* __restrict__ out, int n) {
  int i = blockIdx.x * blockDim.x + threadIdx.x;
  int st = gridDim.x * blockDim.x;
  for (; i < n; i += st) {
    union { f16 h; u16 u; } cv;
    cv.h = (f16)in[i];
    out[i] = cv.u;
  }
}

// ---------- k/v projection (tiny: 5x256 each) ----------
__global__ __launch_bounds__(256) void k_kv(const float* __restrict__ st,
                                            const float* __restrict__ kw,
                                            const float* __restrict__ vw,
                                            const float* __restrict__ inb,
                                            float* __restrict__ kv) {
  int e = threadIdx.x;   // 0..255
  for (int s = 0; s < STOK; ++s) {
    float ak = inb[Hn + e], av = inb[2 * Hn + e];
    for (int d = 0; d < SDIM; ++d) {
      float x = st[s * SDIM + d];
      ak += x * kw[e * SDIM + d];
      av += x * vw[e * SDIM + d];
    }
    kv[s * Hn + e] = ak;
    kv[STOK * Hn + s * Hn + e] = av;
  }
}

// ---------- MFMA GEMM: C[m][n] = scale*(sum_k A[m][k]*B[n][k] + bias[n]) ----------
// A: [M][K] bf16, B: [N][K] bf16 (i.e. X @ W^T). M,N multiples of 128, K arbitrary.
template <bool OUT_BF16>
__global__ __launch_bounds__(256) void k_gemm_bt(const u16* __restrict__ A,
                                                 const u16* __restrict__ B,
                                                 const float* __restrict__ bias,
                                                 float scale, void* __restrict__ Cout,
                                                 int M, int N, int K) {
  constexpr int BM = 128, BN = 128, BK = 32, LDT = 40;  // pad 32->40 elems (80B rows, 16B aligned)
  __shared__ __align__(16) u16 As[BM * LDT];
  __shared__ __align__(16) u16 Bs[BN * LDT];
  const int tid = threadIdx.x;
  const int bm0 = blockIdx.x * BM;
  const int bn0 = blockIdx.y * BN;
  const int lane = tid & 63;
  const int wave = tid >> 6;
  const int wm = (wave & 1) * 64;
  const int wn = (wave >> 1) * 64;
  const int lr = lane & 15;
  const int kg = lane >> 4;
  const int srow = tid >> 1, sch = tid & 1;

  f32x4 acc[4][4] = {};

  for (int k0 = 0; k0 < K; k0 += BK) {
    // stage A tile
    {
      const u16* gp = A + (size_t)(bm0 + srow) * K + k0 + sch * 16;
      u16* lp = &As[srow * LDT + sch * 16];
      if (k0 + BK <= K) {
        *(uint4*)lp = *(const uint4*)gp;
        *(uint4*)(lp + 8) = *(const uint4*)(gp + 8);
      } else {
        for (int i = 0; i < 16; ++i) {
          int k = k0 + sch * 16 + i;
          lp[i] = (k < K) ? gp[i] : (u16)0;
        }
      }
    }
    // stage B tile
    {
      const u16* gp = B + (size_t)(bn0 + srow) * K + k0 + sch * 16;
      u16* lp = &Bs[srow * LDT + sch * 16];
      if (k0 + BK <= K) {
        *(uint4*)lp = *(const uint4*)gp;
        *(uint4*)(lp + 8) = *(const uint4*)(gp + 8);
      } else {
        for (int i = 0; i < 16; ++i) {
          int k = k0 + sch * 16 + i;
          lp[i] = (k < K) ? gp[i] : (u16)0;
        }
      }
    }
    __syncthreads();

    bf16x8 af[4], bfr[4];
#pragma unroll
    for (int mi = 0; mi < 4; ++mi)
      af[mi] = *(const bf16x8*)&As[(wm + mi * 16 + lr) * LDT + kg * 8];
#pragma unroll
    for (int ni = 0; ni < 4; ++ni)
      bfr[ni] = *(const bf16x8*)&Bs[(wn + ni * 16 + lr) * LDT + kg * 8];
#pragma unroll
    for (int mi = 0; mi < 4; ++mi)
#pragma unroll
      for (int ni = 0; ni < 4; ++ni)
        acc[mi][ni] = __builtin_amdgcn_mfma_f32_16x16x32_bf16(af[mi], bfr[ni], acc[mi][ni], 0, 0, 0);
    __syncthreads();
  }

  // epilogue: D mapping col=lane&15, row=(lane>>4)*4+reg  [m89/m91 verified]
#pragma unroll
  for (int mi = 0; mi < 4; ++mi)
#pragma unroll
    for (int ni = 0; ni < 4; ++ni)
#pragma unroll
      for (int r = 0; r < 4; ++r) {
        int row = bm0 + wm + mi * 16 + kg * 4 + r;
        int col = bn0 + wn + ni * 16 + lr;
        float v = acc[mi][ni][r];
        if (bias) v += bias[col];
        v *= scale;
        if (OUT_BF16)
          ((u16*)Cout)[(size_t)row * N + col] = f2bf(v);
        else
          ((float*)Cout)[(size_t)row * N + col] = v;
      }
}

// ---------- GRU scan: one workgroup per batch element, weights register-resident ----------
// Whh2: [768][128] f16-pairs (row j = Whh[j][0..256) as 128 packed half2)
// xg:   [B][T][768] bf16 (x @ Wih^T + bih, precomputed)
// outs: [B][T][256] bf16
//
// waves_per_eu(3,3): pin occupancy at exactly 3 waves/EU (12 waves = 1 block/CU)
// so the allocator gets the full 512/3 = 170-VGPR budget and keeps hw[128] in
// registers (round-1 compile chose 84 VGPRs = 6 waves/EU and spilled hw to
// scratch -> 1.5 us/step, 52% active-CU VALU busy).
__global__ void __launch_bounds__(768)
__attribute__((amdgpu_waves_per_eu(3, 3)))
k_gru(const u32* __restrict__ Whh2,
      const float* __restrict__ bhh,
      const u16* __restrict__ xg,
      u16* __restrict__ outs) {
  const int tid = threadIdx.x;   // 0..767 : gate index j
  const int b = blockIdx.x;      // batch element
  __shared__ __align__(16) f16 hsh[Hn];     // h in f16 for dot2
  __shared__ float ght[G3];
  __shared__ float xgl[G3];

  // load this gate's 256 weights into registers (128 half2 = 128 VGPRs)
  h2 hw[128];
  const h2* wrow = (const h2*)(Whh2 + (size_t)tid * 128);
#pragma unroll
  for (int i = 0; i < 128; ++i) hw[i] = wrow[i];
  const float bh = bhh[tid];

  float hreg = 0.f;
  if (tid < Hn) hsh[tid] = (f16)0.f;

  const u16* xgb = xg + (size_t)b * Tn * G3;
  u16* ob = outs + (size_t)b * Tn * Hn;
  float xcur = bf2f(xgb[tid]);   // t = 0
  __syncthreads();

  for (int t = 0; t < Tn; ++t) {
    // prefetch next step's xg (independent of h -> latency hidden under dot chain)
    float xnext = (t < Tn - 1) ? bf2f(xgb[(size_t)(t + 1) * G3 + tid]) : 0.f;
    xgl[tid] = xcur;

    // gh[j] = Whh[j,:] . h + bhh[j]; h broadcast from LDS via ds_read_b128
    // (32 DS instrs/thread/step instead of 128 scalar ds_read_b32)
    const h8* hp8 = (const h8*)hsh;
    float a0 = bh, a1 = 0.f, a2 = 0.f, a3 = 0.f;
#pragma unroll
    for (int i = 0; i < 32; ++i) {
      h8 hv = hp8[i];
      h2 p0 = __builtin_shufflevector(hv, hv, 0, 1);
      h2 p1 = __builtin_shufflevector(hv, hv, 2, 3);
      h2 p2 = __builtin_shufflevector(hv, hv, 4, 5);
      h2 p3 = __builtin_shufflevector(hv, hv, 6, 7);
      a0 = fdot2f(hw[4 * i + 0], p0, a0);
      a1 = fdot2f(hw[4 * i + 1], p1, a1);
      a2 = fdot2f(hw[4 * i + 2], p2, a2);
      a3 = fdot2f(hw[4 * i + 3], p3, a3);
    }
    ght[tid] = (a0 + a1) + (a2 + a3);
    __syncthreads();

    if (tid < Hn) {
      float xr = xgl[tid], xz = xgl[Hn + tid], xn = xgl[2 * Hn + tid];
      float gr = ght[tid], gz = ght[Hn + tid], gn = ght[2 * Hn + tid];
      float r = 1.f / (1.f + __expf(-(xr + gr)));
      float z = 1.f / (1.f + __expf(-(xz + gz)));
      float n = tanhf(xn + r * gn);
      hreg = (1.f - z) * n + z * hreg;
      ob[(size_t)t * Hn + tid] = f2bf(hreg);
      hsh[tid] = (f16)hreg;
    }
    __syncthreads();
    xcur = xnext;
  }
}

// ---------- attention over 5 style tokens (thread per (b,t) row) ----------
__global__ __launch_bounds__(256) void k_attn(const u16* __restrict__ q,
                                              const float* __restrict__ kv,
                                              u16* __restrict__ ctx) {
  __shared__ float ks[STOK * Hn], vs[STOK * Hn];
  int tid = threadIdx.x;
  for (int i = tid; i < STOK * Hn; i += 256) {
    ks[i] = kv[i];
    vs[i] = kv[STOK * Hn + i];
  }
  __syncthreads();
  size_t row = (size_t)blockIdx.x * 256 + tid;   // b*T + t
  const u16* qr = q + row * Hn;
  u16* cr = ctx + row * Hn;
#pragma unroll
  for (int h = 0; h < 4; ++h) {
    float sc[STOK] = {0.f, 0.f, 0.f, 0.f, 0.f};
    for (int d = 0; d < 64; ++d) {
      float qv = bf2f(qr[h * 64 + d]);
#pragma unroll
      for (int s = 0; s < STOK; ++s) sc[s] += qv * ks[s * Hn + h * 64 + d];
    }
    float m = sc[0];
#pragma unroll
    for (int s = 1; s < STOK; ++s) m = fmaxf(m, sc[s]);
    float p[STOK], sum = 0.f;
#pragma unroll
    for (int s = 0; s < STOK; ++s) { p[s] = __expf(sc[s] - m); sum += p[s]; }
    float inv = 1.f / sum;
    for (int e = 0; e < 64; ++e) {
      float c = 0.f;
#pragma unroll
      for (int s = 0; s < STOK; ++s) c += p[s] * vs[s * Hn + h * 64 + e];
      cr[h * 64 + e] = f2bf(c * inv);
    }
  }
}

// ---------- workspace layout (bytes) ----------
#define WS_XG   ((size_t)0)                         // [B][T][768] bf16 = 100,663,296
#define WS_O0   ((size_t)100663296)                 // [B][T][256] bf16 = 33,554,432
#define WS_O1   ((size_t)134217728)                 // 33,554,432
#define WS_FB   ((size_t)167772160)                 // feats bf16 = 10,485,760
#define WS_W0   ((size_t)178257920)                 // Wih0 bf16 = 122,880
#define WS_W1   ((size_t)178380800)                 // Wih1 bf16 = 393,216
#define WS_QW   ((size_t)178774016)                 // q_w bf16 = 131,072
#define WS_OW   ((size_t)178905088)                 // out_w bf16 = 131,072
#define WS_H0   ((size_t)179036160)                 // Whh0 f16 = 393,216
#define WS_H1   ((size_t)179429376)                 // Whh1 f16 = 393,216
#define WS_KV   ((size_t)179822592)                 // k,v f32 = 10,240
// q and ctx alias the (dead-by-then) xg region:
#define WS_QB   ((size_t)0)                         // [B*T][256] bf16
#define WS_CTX  ((size_t)33554432)                  // [B*T][256] bf16

extern "C" void kernel_launch(void* const* d_in, const int* in_sizes, int n_in,
                              void* d_out, int out_size, void* d_ws, size_t ws_size,
                              hipStream_t stream) {
  const float* feats = (const float*)d_in[0];
  const float* style = (const float*)d_in[1];
  const float* Wih0 = (const float*)d_in[2];
  const float* Whh0 = (const float*)d_in[3];
  const float* bih0 = (const float*)d_in[4];
  const float* bhh0 = (const float*)d_in[5];
  const float* Wih1 = (const float*)d_in[6];
  const float* Whh1 = (const float*)d_in[7];
  const float* bih1 = (const float*)d_in[8];
  const float* bhh1 = (const float*)d_in[9];
  const float* q_w = (const float*)d_in[10];
  const float* k_w = (const float*)d_in[11];
  const float* v_w = (const float*)d_in[12];
  const float* in_b = (const float*)d_in[13];
  const float* out_w = (const float*)d_in[14];
  const float* out_b = (const float*)d_in[15];

  char* ws = (char*)d_ws;
  u16* xg = (u16*)(ws + WS_XG);
  u16* o0 = (u16*)(ws + WS_O0);
  u16* o1 = (u16*)(ws + WS_O1);
  u16* fb = (u16*)(ws + WS_FB);
  u16* w0 = (u16*)(ws + WS_W0);
  u16* w1 = (u16*)(ws + WS_W1);
  u16* qw = (u16*)(ws + WS_QW);
  u16* ow = (u16*)(ws + WS_OW);
  u16* h0 = (u16*)(ws + WS_H0);
  u16* h1 = (u16*)(ws + WS_H1);
  float* kv = (float*)(ws + WS_KV);
  u16* qb = (u16*)(ws + WS_QB);
  u16* ctx = (u16*)(ws + WS_CTX);

  auto cvgrid = [](int n) { int g = (n + 255) / 256; return g > 2048 ? 2048 : g; };

  // conversions
  k_cvt_bf16<<<cvgrid(MROWS * IDIM), 256, 0, stream>>>(feats, fb, MROWS * IDIM);
  k_cvt_bf16<<<cvgrid(G3 * IDIM), 256, 0, stream>>>(Wih0, w0, G3 * IDIM);
  k_cvt_bf16<<<cvgrid(G3 * Hn), 256, 0, stream>>>(Wih1, w1, G3 * Hn);
  k_cvt_bf16<<<cvgrid(Hn * Hn), 256, 0, stream>>>(q_w, qw, Hn * Hn);
  k_cvt_bf16<<<cvgrid(Hn * Hn), 256, 0, stream>>>(out_w, ow, Hn * Hn);
  k_cvt_f16<<<cvgrid(G3 * Hn), 256, 0, stream>>>(Whh0, h0, G3 * Hn);
  k_cvt_f16<<<cvgrid(G3 * Hn), 256, 0, stream>>>(Whh1, h1, G3 * Hn);

  // k/v projections
  k_kv<<<1, 256, 0, stream>>>(style, k_w, v_w, in_b, kv);

  dim3 g768(MROWS / 128, G3 / 128);
  dim3 g256(MROWS / 128, Hn / 128);

  // layer 0
  k_gemm_bt<true><<<g768, 256, 0, stream>>>(fb, w0, bih0, 1.f, xg, MROWS, G3, IDIM);
  k_gru<<<Bn, G3, 0, stream>>>((const u32*)h0, bhh0, xg, o0);
  // layer 1
  k_gemm_bt<true><<<g768, 256, 0, stream>>>(o0, w1, bih1, 1.f, xg, MROWS, G3, Hn);
  k_gru<<<Bn, G3, 0, stream>>>((const u32*)h1, bhh1, xg, o1);
  // attention
  k_gemm_bt<true><<<g256, 256, 0, stream>>>(o1, qw, in_b, 0.125f, qb, MROWS, Hn, Hn);
  k_attn<<<MROWS / 256, 256, 0, stream>>>(qb, kv, ctx);
  // output projection
  k_gemm_bt<false><<<g256, 256, 0, stream>>>(ctx, ow, out_b, 1.f, d_out, MROWS, Hn, Hn);
}

// Round 3
// 2668.045 us; speedup vs baseline: 1.2597x; 1.1496x over previous
//
#include <hip/hip_runtime.h>
#include <hip/hip_bf16.h>
#include <cmath>

typedef unsigned int u32;
typedef unsigned short u16;
typedef _Float16 f16;
typedef f16 h2 __attribute__((ext_vector_type(2)));
typedef f16 h8 __attribute__((ext_vector_type(8)));
typedef short bf16x8 __attribute__((ext_vector_type(8)));
typedef float f32x4 __attribute__((ext_vector_type(4)));

// ---------- sizes ----------
#define Bn 64
#define Tn 1024
#define IDIM 80
#define Hn 256
#define G3 768           // 3*H
#define STOK 5
#define SDIM 128
#define MROWS (Bn*Tn)    // 65536

// ---------- helpers ----------
__device__ __forceinline__ float bf2f(u16 v) { return __uint_as_float(((u32)v) << 16); }
__device__ __forceinline__ u16 f2bf(float f) {
  u32 x = __float_as_uint(f);
  return (u16)((x + 0x7FFFu + ((x >> 16) & 1u)) >> 16);   // RNE
}
__device__ __forceinline__ float fdot2f(h2 a, h2 b, float c) {
#if __has_builtin(__builtin_amdgcn_fdot2)
  return __builtin_amdgcn_fdot2(a, b, c, false);
#else
  return c + (float)a[0] * (float)b[0] + (float)a[1] * (float)b[1];
#endif
}
__device__ __forceinline__ float frcp(float x) {
#if __has_builtin(__builtin_amdgcn_rcpf)
  return __builtin_amdgcn_rcpf(x);
#else
  return 1.f / x;
#endif
}
__device__ __forceinline__ float fsig(float x) { return frcp(1.f + __expf(-x)); }
__device__ __forceinline__ float ftanh(float x) { return 1.f - 2.f * frcp(1.f + __expf(2.f * x)); }
// quad (4-lane) sum via DPP quad_perm: lanes 4m..4m+3 all end with the group total
__device__ __forceinline__ float qsum(float v) {
  v += __int_as_float(__builtin_amdgcn_mov_dpp(__float_as_int(v), 0xB1, 0xF, 0xF, true)); // xor 1
  v += __int_as_float(__builtin_amdgcn_mov_dpp(__float_as_int(v), 0x4E, 0xF, 0xF, true)); // xor 2
  return v;
}
#define W2(x) __builtin_bit_cast(h2, (x))

// ---------- conversion kernels ----------
__global__ void k_cvt_bf16(const float* __restrict__ in, u16* __restrict__ out, int n) {
  int i = blockIdx.x * blockDim.x + threadIdx.x;
  int st = gridDim.x * blockDim.x;
  for (; i < n; i += st) out[i] = f2bf(in[i]);
}

// Pack Whh[768][256] f32 -> per-thread quad-sliced f16 pairs:
// out u32 idx = tau*128 + s*32 + i*4 + p
//   = pack( W[(tau>>2)+192s][64*(tau&3)+8i+2p], W[...][...+1] )
__global__ void k_prep_whh(const float* __restrict__ W, u32* __restrict__ out) {
  int idx = blockIdx.x * 256 + threadIdx.x;
  if (idx >= G3 * 128) return;
  int tau = idx >> 7, rest = idx & 127;
  int s = rest >> 5, i2 = (rest >> 2) & 7, p = rest & 3;
  int r = (tau >> 2) + 192 * s;
  int c = 64 * (tau & 3) + 8 * i2 + 2 * p;
  union { f16 h; u16 u; } a, b;
  a.h = (f16)W[r * Hn + c];
  b.h = (f16)W[r * Hn + c + 1];
  out[idx] = ((u32)b.u << 16) | (u32)a.u;
}

// ---------- k/v projection (tiny: 5x256 each) ----------
__global__ __launch_bounds__(256) void k_kv(const float* __restrict__ st,
                                            const float* __restrict__ kw,
                                            const float* __restrict__ vw,
                                            const float* __restrict__ inb,
                                            float* __restrict__ kv) {
  int e = threadIdx.x;   // 0..255
  for (int s = 0; s < STOK; ++s) {
    float ak = inb[Hn + e], av = inb[2 * Hn + e];
    for (int d = 0; d < SDIM; ++d) {
      float x = st[s * SDIM + d];
      ak += x * kw[e * SDIM + d];
      av += x * vw[e * SDIM + d];
    }
    kv[s * Hn + e] = ak;
    kv[STOK * Hn + s * Hn + e] = av;
  }
}

// ---------- MFMA GEMM: C[m][n] = scale*(sum_k A[m][k]*B[n][k] + bias[n]) ----------
template <bool OUT_BF16>
__global__ __launch_bounds__(256) void k_gemm_bt(const u16* __restrict__ A,
                                                 const u16* __restrict__ B,
                                                 const float* __restrict__ bias,
                                                 float scale, void* __restrict__ Cout,
                                                 int M, int N, int K) {
  constexpr int BM = 128, BN = 128, BK = 32, LDT = 40;
  __shared__ __align__(16) u16 As[BM * LDT];
  __shared__ __align__(16) u16 Bs[BN * LDT];
  const int tid = threadIdx.x;
  const int bm0 = blockIdx.x * BM;
  const int bn0 = blockIdx.y * BN;
  const int lane = tid & 63;
  const int wave = tid >> 6;
  const int wm = (wave & 1) * 64;
  const int wn = (wave >> 1) * 64;
  const int lr = lane & 15;
  const int kg = lane >> 4;
  const int srow = tid >> 1, sch = tid & 1;

  f32x4 acc[4][4] = {};

  for (int k0 = 0; k0 < K; k0 += BK) {
    {
      const u16* gp = A + (size_t)(bm0 + srow) * K + k0 + sch * 16;
      u16* lp = &As[srow * LDT + sch * 16];
      if (k0 + BK <= K) {
        *(uint4*)lp = *(const uint4*)gp;
        *(uint4*)(lp + 8) = *(const uint4*)(gp + 8);
      } else {
        for (int i = 0; i < 16; ++i) {
          int k = k0 + sch * 16 + i;
          lp[i] = (k < K) ? gp[i] : (u16)0;
        }
      }
    }
    {
      const u16* gp = B + (size_t)(bn0 + srow) * K + k0 + sch * 16;
      u16* lp = &Bs[srow * LDT + sch * 16];
      if (k0 + BK <= K) {
        *(uint4*)lp = *(const uint4*)gp;
        *(uint4*)(lp + 8) = *(const uint4*)(gp + 8);
      } else {
        for (int i = 0; i < 16; ++i) {
          int k = k0 + sch * 16 + i;
          lp[i] = (k < K) ? gp[i] : (u16)0;
        }
      }
    }
    __syncthreads();

    bf16x8 af[4], bfr[4];
#pragma unroll
    for (int mi = 0; mi < 4; ++mi)
      af[mi] = *(const bf16x8*)&As[(wm + mi * 16 + lr) * LDT + kg * 8];
#pragma unroll
    for (int ni = 0; ni < 4; ++ni)
      bfr[ni] = *(const bf16x8*)&Bs[(wn + ni * 16 + lr) * LDT + kg * 8];
#pragma unroll
    for (int mi = 0; mi < 4; ++mi)
#pragma unroll
      for (int ni = 0; ni < 4; ++ni)
        acc[mi][ni] = __builtin_amdgcn_mfma_f32_16x16x32_bf16(af[mi], bfr[ni], acc[mi][ni], 0, 0, 0);
    __syncthreads();
  }

#pragma unroll
  for (int mi = 0; mi < 4; ++mi)
#pragma unroll
    for (int ni = 0; ni < 4; ++ni)
#pragma unroll
      for (int r = 0; r < 4; ++r) {
        int row = bm0 + wm + mi * 16 + kg * 4 + r;
        int col = bn0 + wn + ni * 16 + lr;
        float v = acc[mi][ni][r];
        if (bias) v += bias[col];
        v *= scale;
        if (OUT_BF16)
          ((u16*)Cout)[(size_t)row * N + col] = f2bf(v);
        else
          ((float*)Cout)[(size_t)row * N + col] = v;
      }
}

// ---------- GRU scan ----------
// One workgroup (768 thr) per batch element. Thread tau: quad-sliced matvec —
// quarter q = tau&3 of k-range, rows {r0, r0+192, r0+384, r0+576}, r0 = tau>>2.
// Weights register-resident: 128 u32 (f16 pairs), asm-pinned. h kept in LDS in a
// quarter-interleaved layout: h-index k lives at f16 idx (k&7) + ((k>>3)&7)*32 + (k>>6)*8
// so round i / quarter q reads 16B at byte (i*4+q)*16 -> 4 distinct bank groups,
// 16-lane broadcast, conflict-free. Quad reduce = 2 DPP quad_perm adds (VALU).
__global__ void __launch_bounds__(768)
__attribute__((amdgpu_waves_per_eu(3, 3)))
k_gru(const u32* __restrict__ Wp,
      const float* __restrict__ bhh,
      const u16* __restrict__ xg,
      u16* __restrict__ outs) {
  const int tid = threadIdx.x;
  const int b = blockIdx.x;
  const int q = tid & 3;
  const int r0 = tid >> 2;
  __shared__ __align__(16) f16 hsh[Hn];    // quarter-interleaved
  __shared__ float ght[G3];                // natural row index

  // weights -> registers, pinned
  u32 wv[128];
  {
    const uint4* wp = (const uint4*)(Wp + (size_t)tid * 128);
#pragma unroll
    for (int i = 0; i < 32; ++i) ((uint4*)wv)[i] = wp[i];
  }
#pragma unroll
  for (int i = 0; i < 128; ++i) asm volatile("" : "+v"(wv[i]));

  // gate-thread constants and state
  float b0 = 0.f, b1 = 0.f, b2 = 0.f;
  int hidx = 0;
  if (tid < Hn) {
    b0 = bhh[tid]; b1 = bhh[tid + Hn]; b2 = bhh[tid + 2 * Hn];
    hidx = (tid & 7) + ((tid >> 3) & 7) * 32 + (tid >> 6) * 8;
  }
  float hreg = 0.f;
  if (tid < 128) ((h2*)hsh)[tid] = h2{(f16)0.f, (f16)0.f};

  const u16* xgb = xg + (size_t)b * Tn * G3;
  u16* ob = outs + (size_t)b * Tn * Hn;
  const f16* hbase = hsh + q * 8;

  // x prefetch (t=0)
  float xrc = 0.f, xzc = 0.f, xnc = 0.f;
  if (tid < Hn) {
    xrc = bf2f(xgb[tid]); xzc = bf2f(xgb[tid + Hn]); xnc = bf2f(xgb[tid + 2 * Hn]);
  }
  __syncthreads();

  for (int t = 0; t < Tn; ++t) {
    // prefetch next step's x (independent of h; hidden under dot phase)
    float xrn = 0.f, xzn = 0.f, xnn = 0.f;
    if (tid < Hn) {
      int tc = (t + 1 < Tn) ? t + 1 : t;
      const u16* xrow = xgb + (size_t)tc * G3;
      xrn = bf2f(xrow[tid]); xzn = bf2f(xrow[tid + Hn]); xnn = bf2f(xrow[tid + 2 * Hn]);
    }

    // dot phase: 8 rounds x (1 ds_read_b128 + 16 dot2)
    float acc0 = 0.f, acc1 = 0.f, acc2 = 0.f, acc3 = 0.f;
#pragma unroll
    for (int i = 0; i < 8; ++i) {
      h8 hv = *(const h8*)(hbase + i * 32);
      h2 p0 = __builtin_shufflevector(hv, hv, 0, 1);
      h2 p1 = __builtin_shufflevector(hv, hv, 2, 3);
      h2 p2 = __builtin_shufflevector(hv, hv, 4, 5);
      h2 p3 = __builtin_shufflevector(hv, hv, 6, 7);
      acc0 = fdot2f(W2(wv[i * 4 + 0]), p0, acc0);
      acc0 = fdot2f(W2(wv[i * 4 + 1]), p1, acc0);
      acc0 = fdot2f(W2(wv[i * 4 + 2]), p2, acc0);
      acc0 = fdot2f(W2(wv[i * 4 + 3]), p3, acc0);
      acc1 = fdot2f(W2(wv[32 + i * 4 + 0]), p0, acc1);
      acc1 = fdot2f(W2(wv[32 + i * 4 + 1]), p1, acc1);
      acc1 = fdot2f(W2(wv[32 + i * 4 + 2]), p2, acc1);
      acc1 = fdot2f(W2(wv[32 + i * 4 + 3]), p3, acc1);
      acc2 = fdot2f(W2(wv[64 + i * 4 + 0]), p0, acc2);
      acc2 = fdot2f(W2(wv[64 + i * 4 + 1]), p1, acc2);
      acc2 = fdot2f(W2(wv[64 + i * 4 + 2]), p2, acc2);
      acc2 = fdot2f(W2(wv[64 + i * 4 + 3]), p3, acc2);
      acc3 = fdot2f(W2(wv[96 + i * 4 + 0]), p0, acc3);
      acc3 = fdot2f(W2(wv[96 + i * 4 + 1]), p1, acc3);
      acc3 = fdot2f(W2(wv[96 + i * 4 + 2]), p2, acc3);
      acc3 = fdot2f(W2(wv[96 + i * 4 + 3]), p3, acc3);
    }
    acc0 = qsum(acc0); acc1 = qsum(acc1); acc2 = qsum(acc2); acc3 = qsum(acc3);
    float sel = (q == 0) ? acc0 : (q == 1) ? acc1 : (q == 2) ? acc2 : acc3;
    ght[r0 + 192 * q] = sel;
    __syncthreads();

    if (tid < Hn) {
      float gr = ght[tid] + b0;
      float gz = ght[tid + Hn] + b1;
      float gn = ght[tid + 2 * Hn] + b2;
      float r = fsig(xrc + gr);
      float z = fsig(xzc + gz);
      float n = ftanh(xnc + r * gn);
      hreg = (1.f - z) * n + z * hreg;
      ob[(size_t)t * Hn + tid] = f2bf(hreg);
      hsh[hidx] = (f16)hreg;
    }
    __syncthreads();
    xrc = xrn; xzc = xzn; xnc = xnn;
  }
}

// ---------- attention over 5 style tokens (thread per (b,t) row) ----------
__global__ __launch_bounds__(256) void k_attn(const u16* __restrict__ q,
                                              const float* __restrict__ kv,
                                              u16* __restrict__ ctx) {
  __shared__ float ks[STOK * Hn], vs[STOK * Hn];
  int tid = threadIdx.x;
  for (int i = tid; i < STOK * Hn; i += 256) {
    ks[i] = kv[i];
    vs[i] = kv[STOK * Hn + i];
  }
  __syncthreads();
  size_t row = (size_t)blockIdx.x * 256 + tid;
  const u16* qr = q + row * Hn;
  u16* cr = ctx + row * Hn;
#pragma unroll
  for (int h = 0; h < 4; ++h) {
    float sc[STOK] = {0.f, 0.f, 0.f, 0.f, 0.f};
    for (int d = 0; d < 64; ++d) {
      float qv = bf2f(qr[h * 64 + d]);
#pragma unroll
      for (int s = 0; s < STOK; ++s) sc[s] += qv * ks[s * Hn + h * 64 + d];
    }
    float m = sc[0];
#pragma unroll
    for (int s = 1; s < STOK; ++s) m = fmaxf(m, sc[s]);
    float p[STOK], sum = 0.f;
#pragma unroll
    for (int s = 0; s < STOK; ++s) { p[s] = __expf(sc[s] - m); sum += p[s]; }
    float inv = 1.f / sum;
    for (int e = 0; e < 64; ++e) {
      float c = 0.f;
#pragma unroll
      for (int s = 0; s < STOK; ++s) c += p[s] * vs[s * Hn + h * 64 + e];
      cr[h * 64 + e] = f2bf(c * inv);
    }
  }
}

// ---------- workspace layout (bytes) ----------
#define WS_XG   ((size_t)0)                         // [B][T][768] bf16 = 100,663,296
#define WS_O0   ((size_t)100663296)                 // [B][T][256] bf16 = 33,554,432
#define WS_O1   ((size_t)134217728)                 // 33,554,432
#define WS_FB   ((size_t)167772160)                 // feats bf16 = 10,485,760
#define WS_W0   ((size_t)178257920)                 // Wih0 bf16 = 122,880
#define WS_W1   ((size_t)178380800)                 // Wih1 bf16 = 393,216
#define WS_QW   ((size_t)178774016)                 // q_w bf16 = 131,072
#define WS_OW   ((size_t)178905088)                 // out_w bf16 = 131,072
#define WS_H0   ((size_t)179036160)                 // Whh0 prepped u32 = 393,216
#define WS_H1   ((size_t)179429376)                 // Whh1 prepped u32 = 393,216
#define WS_KV   ((size_t)179822592)                 // k,v f32 = 10,240
#define WS_QB   ((size_t)0)                         // q aliases dead xg
#define WS_CTX  ((size_t)33554432)                  // ctx aliases dead xg

extern "C" void kernel_launch(void* const* d_in, const int* in_sizes, int n_in,
                              void* d_out, int out_size, void* d_ws, size_t ws_size,
                              hipStream_t stream) {
  const float* feats = (const float*)d_in[0];
  const float* style = (const float*)d_in[1];
  const float* Wih0 = (const float*)d_in[2];
  const float* Whh0 = (const float*)d_in[3];
  const float* bih0 = (const float*)d_in[4];
  const float* bhh0 = (const float*)d_in[5];
  const float* Wih1 = (const float*)d_in[6];
  const float* Whh1 = (const float*)d_in[7];
  const float* bih1 = (const float*)d_in[8];
  const float* bhh1 = (const float*)d_in[9];
  const float* q_w = (const float*)d_in[10];
  const float* k_w = (const float*)d_in[11];
  const float* v_w = (const float*)d_in[12];
  const float* in_b = (const float*)d_in[13];
  const float* out_w = (const float*)d_in[14];
  const float* out_b = (const float*)d_in[15];

  char* ws = (char*)d_ws;
  u16* xg = (u16*)(ws + WS_XG);
  u16* o0 = (u16*)(ws + WS_O0);
  u16* o1 = (u16*)(ws + WS_O1);
  u16* fb = (u16*)(ws + WS_FB);
  u16* w0 = (u16*)(ws + WS_W0);
  u16* w1 = (u16*)(ws + WS_W1);
  u16* qw = (u16*)(ws + WS_QW);
  u16* ow = (u16*)(ws + WS_OW);
  u32* h0 = (u32*)(ws + WS_H0);
  u32* h1 = (u32*)(ws + WS_H1);
  float* kv = (float*)(ws + WS_KV);
  u16* qb = (u16*)(ws + WS_QB);
  u16* ctx = (u16*)(ws + WS_CTX);

  auto cvgrid = [](int n) { int g = (n + 255) / 256; return g > 2048 ? 2048 : g; };

  // conversions / weight prep
  k_cvt_bf16<<<cvgrid(MROWS * IDIM), 256, 0, stream>>>(feats, fb, MROWS * IDIM);
  k_cvt_bf16<<<cvgrid(G3 * IDIM), 256, 0, stream>>>(Wih0, w0, G3 * IDIM);
  k_cvt_bf16<<<cvgrid(G3 * Hn), 256, 0, stream>>>(Wih1, w1, G3 * Hn);
  k_cvt_bf16<<<cvgrid(Hn * Hn), 256, 0, stream>>>(q_w, qw, Hn * Hn);
  k_cvt_bf16<<<cvgrid(Hn * Hn), 256, 0, stream>>>(out_w, ow, Hn * Hn);
  k_prep_whh<<<(G3 * 128 + 255) / 256, 256, 0, stream>>>(Whh0, h0);
  k_prep_whh<<<(G3 * 128 + 255) / 256, 256, 0, stream>>>(Whh1, h1);

  k_kv<<<1, 256, 0, stream>>>(style, k_w, v_w, in_b, kv);

  dim3 g768(MROWS / 128, G3 / 128);
  dim3 g256(MROWS / 128, Hn / 128);

  // layer 0
  k_gemm_bt<true><<<g768, 256, 0, stream>>>(fb, w0, bih0, 1.f, xg, MROWS, G3, IDIM);
  k_gru<<<Bn, G3, 0, stream>>>(h0, bhh0, xg, o0);
  // layer 1
  k_gemm_bt<true><<<g768, 256, 0, stream>>>(o0, w1, bih1, 1.f, xg, MROWS, G3, Hn);
  k_gru<<<Bn, G3, 0, stream>>>(h1, bhh1, xg, o1);
  // attention
  k_gemm_bt<true><<<g256, 256, 0, stream>>>(o1, qw, in_b, 0.125f, qb, MROWS, Hn, Hn);
  k_attn<<<MROWS / 256, 256, 0, stream>>>(qb, kv, ctx);
  // output projection
  k_gemm_bt<false><<<g256, 256, 0, stream>>>(ctx, ow, out_b, 1.f, d_out, MROWS, Hn, Hn);
}